// Round 6
// baseline (2116.523 us; speedup 1.0000x reference)
//
#include <hip/hip_runtime.h>
#include <hip/hip_bf16.h>

#define T_STEPS 32
#define BATCH 256
#define EDIM 512
#define HDIM 512
#define G4 2048       // 4*H
#define VOCAB 3000
#define VPAD 3072

typedef short bf16x8 __attribute__((ext_vector_type(8)));
typedef float f32x4 __attribute__((ext_vector_type(4)));

__device__ __forceinline__ unsigned short f2b(float f){
  union { float f; unsigned int u; } x; x.f = f;
  unsigned int u = x.u;
  unsigned int r = (u + 0x7fffu + ((u >> 16) & 1u)) >> 16;
  return (unsigned short)r;
}
__device__ __forceinline__ float b2f(unsigned short h){
  union { unsigned int u; float f; } x; x.u = ((unsigned int)h) << 16;
  return x.f;
}
// fast sigmoid/tanh: v_exp + v_rcp (≈1 ulp each; error ≪ bf16 rounding budget)
__device__ __forceinline__ float fsigm(float x){
  return __builtin_amdgcn_rcpf(1.0f + __expf(-x));
}
__device__ __forceinline__ float ftanh(float x){
  return 1.0f - 2.0f * __builtin_amdgcn_rcpf(1.0f + __expf(2.0f * x));
}
__device__ __forceinline__ float sigm(float x){ return 1.0f / (1.0f + expf(-x)); }

__device__ __forceinline__ void gload_lds16(const unsigned short* g, unsigned short* l){
  __builtin_amdgcn_global_load_lds(
      (const __attribute__((address_space(1))) unsigned int*)g,
      (__attribute__((address_space(3))) unsigned int*)l, 16, 0, 0);
}

// ---------------- small prep kernels ----------------

__global__ void k_cvt(const float* __restrict__ in, unsigned short* __restrict__ out, int n){
  int i = blockIdx.x * blockDim.x + threadIdx.x;
  if (i < n) out[i] = f2b(in[i]);
}

__global__ void k_cvt_wout(const float* __restrict__ in, unsigned short* __restrict__ out){
  int i = blockIdx.x * blockDim.x + threadIdx.x; // over VPAD*1024
  if (i >= VPAD * 1024) return;
  int r = i >> 10, c = i & 1023;
  float v = (r < VOCAB) ? in[r * 1024 + c] : 0.0f;
  out[i] = f2b(v);
}

__global__ void k_build_xs(const float* __restrict__ img, const float* __restrict__ txt,
                           const float* __restrict__ emb, const int* __restrict__ ans,
                           unsigned short* __restrict__ xs){
  int i = blockIdx.x * blockDim.x + threadIdx.x; // over T*B*E
  if (i >= T_STEPS * BATCH * EDIM) return;
  int e = i & (EDIM - 1);
  int r = i >> 9;              // t*B + b
  int t = r >> 8, b = r & 255;
  float v;
  if (t == 0) v = (e < 256) ? img[b * 256 + e] : txt[b * 256 + (e - 256)];
  else { int tok = ans[b * T_STEPS + (t - 1)]; v = emb[(size_t)tok * EDIM + e]; }
  xs[i] = f2b(v);
}

// batch_sizes, packed row offsets, total rows, dest->src row map
__global__ void k_lens(const int* __restrict__ lengths, int* __restrict__ bs,
                       int* __restrict__ roff, int* __restrict__ meta,
                       int* __restrict__ rmap){
  __shared__ int s[T_STEPS];
  __shared__ int sroff[T_STEPS + 1];
  int t = threadIdx.x; // 64 threads
  if (t < T_STEPS){
    int c = 0;
    for (int i = 0; i < BATCH; i++) c += (lengths[i] > t) ? 1 : 0;
    s[t] = c; bs[t] = c;
  }
  __syncthreads();
  if (t == 0){
    int acc = 0;
    for (int u = 0; u < T_STEPS; u++){ sroff[u] = acc; roff[u] = acc; acc += s[u]; }
    sroff[T_STEPS] = acc;
    meta[0] = acc;
  }
  __syncthreads();
  int ntot = sroff[T_STEPS];
  for (int r = t; r < T_STEPS * BATCH; r += 64){
    int tt = r >> 8, b = r & 255;
    if (b < s[tt]) rmap[sroff[tt] + b] = r;
  }
  for (int r = ntot + t; r < T_STEPS * BATCH; r += 64) rmap[r] = -1;
}

// ---------------- staged 128x128 GEMM core, BK=64, XOR-swizzled LDS ----------------
template<int K>
__device__ __forceinline__ void gemm_tile(const unsigned short* __restrict__ A,
                                          const unsigned short* __restrict__ B,
                                          int row0, int col0,
                                          unsigned short* As, unsigned short* Bs,
                                          f32x4 acc[4][4]){
  const int tid = threadIdx.x, w = tid >> 6, l = tid & 63;
  const int la = l & 15, lkq = l >> 4;
  const int sr = l >> 3;            // row within 8-row staging group
  const int ss = (l & 7) ^ sr;      // pre-swizzled source slot
  const int wr = (w >> 1) * 64, wc = (w & 1) * 64;
  const unsigned short* gA = A + (size_t)(row0 + w * 32 + sr) * K + ss * 8;
  const unsigned short* gB = B + (size_t)(col0 + w * 32 + sr) * K + ss * 8;
  unsigned short* lA = As + (w * 32) * 64;
  unsigned short* lB = Bs + (w * 32) * 64;
  for (int k0 = 0; k0 < K; k0 += 64){
#pragma unroll
    for (int i = 0; i < 4; i++){
      gload_lds16(gA + (size_t)i * 8 * K + k0, lA + i * 8 * 64);
      gload_lds16(gB + (size_t)i * 8 * K + k0, lB + i * 8 * 64);
    }
    __syncthreads();
#pragma unroll
    for (int kk = 0; kk < 2; kk++){
      bf16x8 a[4], b[4];
#pragma unroll
      for (int i = 0; i < 4; i++){
        int r = wr + i * 16 + la;
        a[i] = *(const bf16x8*)(As + r * 64 + (((kk * 4 + lkq) ^ (r & 7)) << 3));
      }
#pragma unroll
      for (int i = 0; i < 4; i++){
        int r = wc + i * 16 + la;
        b[i] = *(const bf16x8*)(Bs + r * 64 + (((kk * 4 + lkq) ^ (r & 7)) << 3));
      }
#pragma unroll
      for (int mi = 0; mi < 4; mi++)
#pragma unroll
        for (int ni = 0; ni < 4; ni++)
          acc[mi][ni] = __builtin_amdgcn_mfma_f32_16x16x32_bf16(a[mi], b[ni], acc[mi][ni], 0, 0, 0);
    }
    __syncthreads();
  }
}

// ---------------- GEMM 1: XW = xs @ W_ih^T + b_ih + b_hh (bf16 out) ----------------
__global__ __launch_bounds__(256) void k_gemm_xw(const unsigned short* __restrict__ A,
                                                 const unsigned short* __restrict__ W,
                                                 const float* __restrict__ bih,
                                                 const float* __restrict__ bhh,
                                                 unsigned short* __restrict__ C){
  __shared__ unsigned short As[128 * 64], Bs[128 * 64];
  int row0 = blockIdx.x * 128, col0 = blockIdx.y * 128;
  f32x4 acc[4][4] = {};
  gemm_tile<EDIM>(A, W, row0, col0, As, Bs, acc);
  int tid = threadIdx.x, w = tid >> 6, l = tid & 63;
  int la = l & 15, r4 = (l >> 4) * 4;
  int wr = (w >> 1) * 64, wc = (w & 1) * 64;
#pragma unroll
  for (int ni = 0; ni < 4; ni++){
    int col = col0 + wc + ni * 16 + la;
    float bias = bih[col] + bhh[col];
#pragma unroll
    for (int mi = 0; mi < 4; mi++)
#pragma unroll
      for (int j = 0; j < 4; j++){
        int row = row0 + wr + mi * 16 + r4 + j;
        C[(size_t)row * G4 + col] = f2b(acc[mi][ni][j] + bias);
      }
  }
}

// ---------------- fully-fused LSTM chain: 16 blocks x 1024 thr, one launch ----------------
// Block owns 16 batch rows for ALL 32 steps (row-independent recurrence -> no grid sync).
// Wave w owns h-cols [32w,32w+32) and all 4 gates for them; cell update is lane-local.
// h state in LDS (swizzled); c + skip history in registers; W_hh re-read from L2 each step.
__global__ __launch_bounds__(1024) void k_lstm_fused(
    const unsigned short* __restrict__ XW,   // [T][B][2048] bf16
    const unsigned short* __restrict__ Whh,  // [2048][512] bf16
    const float* __restrict__ h0,
    const float* __restrict__ c0,
    unsigned short* __restrict__ hs,
    unsigned short* __restrict__ cs){
  __shared__ unsigned short hL[16 * 512];
  const int tid = threadIdx.x;
  const int w = tid >> 6, l = tid & 63;
  const int la = l & 15, lkq = l >> 4;
  const int row0 = blockIdx.x * 16;
  // ---- init hL from h0 (bf16, swizzled 16B slots: slot ^= row&7) ----
  {
    int r = w;                 // 0..15
    int c8 = l * 8;            // 0..504
    const float* hp = h0 + (size_t)(row0 + r) * HDIM + c8;
    bf16x8 hv;
#pragma unroll
    for (int j = 0; j < 8; j++) hv[j] = (short)f2b(hp[j]);
    *(bf16x8*)(hL + r * 512 + (((c8 >> 3) ^ (r & 7)) << 3)) = hv;
  }
  // ---- per-thread state: 8 cells at rows lkq*4+j, cols w*32 + nt*16 + la ----
  float cx[2][4];
  unsigned hm1h[2][2], hm1c[2][2], hm2h[2][2], hm2c[2][2];  // bf16-packed history
#pragma unroll
  for (int nt = 0; nt < 2; nt++){
#pragma unroll
    for (int j = 0; j < 4; j++)
      cx[nt][j] = c0[(size_t)(row0 + lkq * 4 + j) * HDIM + w * 32 + nt * 16 + la];
    hm1h[nt][0] = hm1h[nt][1] = hm1c[nt][0] = hm1c[nt][1] = 0u;
    hm2h[nt][0] = hm2h[nt][1] = hm2c[nt][0] = hm2c[nt][1] = 0u;
  }
  __syncthreads();
  const unsigned short* bbase = Whh + (size_t)(w * 32 + la) * HDIM + lkq * 8;
  for (int t = 0; t < T_STEPS; t++){
    // prefetch XW for this step (consumed after MFMA)
    float xwf[4][2][4];
    {
      const unsigned short* xp = XW + (size_t)t * BATCH * G4
                               + (size_t)(row0 + lkq * 4) * G4 + w * 32 + la;
#pragma unroll
      for (int g = 0; g < 4; g++)
#pragma unroll
        for (int nt = 0; nt < 2; nt++)
#pragma unroll
          for (int j = 0; j < 4; j++)
            xwf[g][nt][j] = b2f(xp[(size_t)j * G4 + g * 512 + nt * 16]);
    }
    // gates = h @ Whh^T : A-frags from LDS, B-frags flat from L2-resident Whh
    f32x4 acc[4][2] = {};
#pragma unroll
    for (int kk = 0; kk < 16; kk++){
      bf16x8 a = *(const bf16x8*)(hL + la * 512 + (((kk * 4 + lkq) ^ (la & 7)) << 3));
#pragma unroll
      for (int g = 0; g < 4; g++)
#pragma unroll
        for (int nt = 0; nt < 2; nt++){
          bf16x8 b = *(const bf16x8*)(bbase + (size_t)(g * 512 + nt * 16) * HDIM + kk * 32);
          acc[g][nt] = __builtin_amdgcn_mfma_f32_16x16x32_bf16(a, b, acc[g][nt], 0, 0, 0);
        }
    }
    __syncthreads();   // all waves done reading hL
    const int do_res = (t >= 2) && (t % 3 == 0);
    unsigned short* hsr = hs + (size_t)t * BATCH * HDIM;
    unsigned short* csr = cs + (size_t)t * BATCH * HDIM;
#pragma unroll
    for (int nt = 0; nt < 2; nt++){
      unsigned short hyb[4], cyb[4];
#pragma unroll
      for (int j = 0; j < 4; j++){
        float gi = acc[0][nt][j] + xwf[0][nt][j];
        float gf = acc[1][nt][j] + xwf[1][nt][j];
        float gg = acc[2][nt][j] + xwf[2][nt][j];
        float go = acc[3][nt][j] + xwf[3][nt][j];
        float cy = fsigm(gf) * cx[nt][j] + fsigm(gi) * ftanh(gg);
        float hy = fsigm(go) * ftanh(cy);
        hyb[j] = f2b(hy); cyb[j] = f2b(cy);
        int r = lkq * 4 + j, c = w * 32 + nt * 16 + la;
        size_t p = (size_t)(row0 + r) * HDIM + c;
        hsr[p] = hyb[j]; csr[p] = cyb[j];
        float hn = hy, cn = cy;
        if (do_res){
          unsigned h2 = hm2h[nt][j >> 1], c2 = hm2c[nt][j >> 1];
          unsigned short hh = (j & 1) ? (unsigned short)(h2 >> 16) : (unsigned short)(h2 & 0xffffu);
          unsigned short ch = (j & 1) ? (unsigned short)(c2 >> 16) : (unsigned short)(c2 & 0xffffu);
          hn += b2f(hh); cn += b2f(ch);
        }
        cx[nt][j] = cn;
        hL[r * 512 + ((((c >> 3) ^ (r & 7)) << 3) | (c & 7))] = f2b(hn);
      }
      hm2h[nt][0] = hm1h[nt][0]; hm2h[nt][1] = hm1h[nt][1];
      hm2c[nt][0] = hm1c[nt][0]; hm2c[nt][1] = hm1c[nt][1];
      hm1h[nt][0] = (unsigned)hyb[0] | ((unsigned)hyb[1] << 16);
      hm1h[nt][1] = (unsigned)hyb[2] | ((unsigned)hyb[3] << 16);
      hm1c[nt][0] = (unsigned)cyb[0] | ((unsigned)cyb[1] << 16);
      hm1c[nt][1] = (unsigned)cyb[2] | ((unsigned)cyb[3] << 16);
    }
    __syncthreads();   // hL(t) fully written before next step's reads
  }
}

// ---------------- GEMM 2: packed output projection, A gathered via rmap ----------------
__global__ __launch_bounds__(256) void k_gemm_out(const unsigned short* __restrict__ hs,
                                                  const unsigned short* __restrict__ cs,
                                                  const unsigned short* __restrict__ Wo,
                                                  const float* __restrict__ bout,
                                                  const int* __restrict__ meta,
                                                  const int* __restrict__ rmap,
                                                  float* __restrict__ out){
  int ntot = meta[0];
  int row0 = blockIdx.x * 128, col0 = blockIdx.y * 128;
  if (row0 >= ntot) return;
  __shared__ unsigned short As[128 * 64], Bs[128 * 64];
  const int tid = threadIdx.x, w = tid >> 6, l = tid & 63;
  const int la = l & 15, lkq = l >> 4;
  const int sr = l >> 3, ss = (l & 7) ^ sr;
  const int wr = (w >> 1) * 64, wc = (w & 1) * 64;
  int srow[4];
#pragma unroll
  for (int i = 0; i < 4; i++){
    int rr = rmap[row0 + w * 32 + sr + i * 8];
    srow[i] = rr < 0 ? 0 : rr;
  }
  const unsigned short* gB = Wo + (size_t)(col0 + w * 32 + sr) * 1024 + ss * 8;
  unsigned short* lA = As + (w * 32) * 64;
  unsigned short* lB = Bs + (w * 32) * 64;
  f32x4 acc[4][4] = {};
  for (int k0 = 0; k0 < 1024; k0 += 64){
#pragma unroll
    for (int i = 0; i < 4; i++){
      const unsigned short* srcA = (k0 < 512)
          ? hs + (size_t)srow[i] * 512 + k0 + ss * 8
          : cs + (size_t)srow[i] * 512 + (k0 - 512) + ss * 8;
      gload_lds16(srcA, lA + i * 8 * 64);
      gload_lds16(gB + (size_t)i * 8 * 1024 + k0, lB + i * 8 * 64);
    }
    __syncthreads();
#pragma unroll
    for (int kk = 0; kk < 2; kk++){
      bf16x8 a[4], b[4];
#pragma unroll
      for (int i = 0; i < 4; i++){
        int r = wr + i * 16 + la;
        a[i] = *(const bf16x8*)(As + r * 64 + (((kk * 4 + lkq) ^ (r & 7)) << 3));
      }
#pragma unroll
      for (int i = 0; i < 4; i++){
        int r = wc + i * 16 + la;
        b[i] = *(const bf16x8*)(Bs + r * 64 + (((kk * 4 + lkq) ^ (r & 7)) << 3));
      }
#pragma unroll
      for (int mi = 0; mi < 4; mi++)
#pragma unroll
        for (int ni = 0; ni < 4; ni++)
          acc[mi][ni] = __builtin_amdgcn_mfma_f32_16x16x32_bf16(a[mi], b[ni], acc[mi][ni], 0, 0, 0);
    }
    __syncthreads();
  }
  int r4 = (l >> 4) * 4;
#pragma unroll
  for (int ni = 0; ni < 4; ni++){
    int col = col0 + wc + ni * 16 + la;
    if (col >= VOCAB) continue;
    float bias = bout[col];
#pragma unroll
    for (int mi = 0; mi < 4; mi++)
#pragma unroll
      for (int j = 0; j < 4; j++){
        int row = row0 + wr + mi * 16 + r4 + j;
        if (row < ntot) out[(size_t)row * VOCAB + col] = acc[mi][ni][j] + bias;
      }
  }
}

extern "C" void kernel_launch(void* const* d_in, const int* in_sizes, int n_in,
                              void* d_out, int out_size, void* d_ws, size_t ws_size,
                              hipStream_t stream){
  const float* img   = (const float*)d_in[0];
  const float* txt   = (const float*)d_in[1];
  const float* h0    = (const float*)d_in[2];
  const float* c0    = (const float*)d_in[3];
  const float* emb   = (const float*)d_in[4];
  const float* W_ih  = (const float*)d_in[5];
  const float* W_hh  = (const float*)d_in[6];
  const float* b_ih  = (const float*)d_in[7];
  const float* b_hh  = (const float*)d_in[8];
  const float* W_out = (const float*)d_in[9];
  const float* b_out = (const float*)d_in[10];
  const int* answer  = (const int*)d_in[11];
  const int* lengths = (const int*)d_in[12];
  float* out = (float*)d_out;

  char* ws = (char*)d_ws;
  size_t off = 0;
  auto alloc = [&](size_t bytes) -> void* {
    void* p = ws + off; off += (bytes + 255) & ~(size_t)255; return p;
  };
  unsigned short* Wih_b = (unsigned short*)alloc((size_t)G4 * EDIM * 2);
  unsigned short* Whh_b = (unsigned short*)alloc((size_t)G4 * HDIM * 2);
  unsigned short* Wo_b  = (unsigned short*)alloc((size_t)VPAD * 1024 * 2);
  unsigned short* xs    = (unsigned short*)alloc((size_t)T_STEPS * BATCH * EDIM * 2);
  unsigned short* XW    = (unsigned short*)alloc((size_t)T_STEPS * BATCH * G4 * 2);
  unsigned short* hs    = (unsigned short*)alloc((size_t)T_STEPS * BATCH * HDIM * 2);
  unsigned short* cs    = (unsigned short*)alloc((size_t)T_STEPS * BATCH * HDIM * 2);
  int* bsz  = (int*)alloc(T_STEPS * 4);
  int* roff = (int*)alloc(T_STEPS * 4);
  int* meta = (int*)alloc(256);
  int* rmap = (int*)alloc(T_STEPS * BATCH * 4);

  k_cvt<<<(G4 * EDIM + 255) / 256, 256, 0, stream>>>(W_ih, Wih_b, G4 * EDIM);
  k_cvt<<<(G4 * HDIM + 255) / 256, 256, 0, stream>>>(W_hh, Whh_b, G4 * HDIM);
  k_cvt_wout<<<(VPAD * 1024 + 255) / 256, 256, 0, stream>>>(W_out, Wo_b);
  k_build_xs<<<(T_STEPS * BATCH * EDIM + 255) / 256, 256, 0, stream>>>(img, txt, emb, answer, xs);
  k_lens<<<1, 64, 0, stream>>>(lengths, bsz, roff, meta, rmap);

  k_gemm_xw<<<dim3(T_STEPS * BATCH / 128, G4 / 128), 256, 0, stream>>>(xs, Wih_b, b_ih, b_hh, XW);

  k_lstm_fused<<<dim3(BATCH / 16), 1024, 0, stream>>>(XW, Whh_b, h0, c0, hs, cs);

  k_gemm_out<<<dim3(T_STEPS * BATCH / 128, VPAD / 128), 256, 0, stream>>>(hs, cs, Wo_b, b_out, meta, rmap, out);
}

// Round 7
// 355.421 us; speedup vs baseline: 5.9550x; 5.9550x over previous
//
#include <hip/hip_runtime.h>
#include <hip/hip_bf16.h>

#define T_STEPS 32
#define BATCH 256
#define EDIM 512
#define HDIM 512
#define G4 2048       // 4*H
#define VOCAB 3000
#define VPAD 3072

typedef short bf16x8 __attribute__((ext_vector_type(8)));
typedef float f32x4 __attribute__((ext_vector_type(4)));

__device__ __forceinline__ unsigned short f2b(float f){
  union { float f; unsigned int u; } x; x.f = f;
  unsigned int u = x.u;
  unsigned int r = (u + 0x7fffu + ((u >> 16) & 1u)) >> 16;
  return (unsigned short)r;
}
__device__ __forceinline__ float b2f(unsigned short h){
  union { unsigned int u; float f; } x; x.u = ((unsigned int)h) << 16;
  return x.f;
}
__device__ __forceinline__ float sigm(float x){ return 1.0f / (1.0f + expf(-x)); }

__device__ __forceinline__ void gload_lds16(const unsigned short* g, unsigned short* l){
  __builtin_amdgcn_global_load_lds(
      (const __attribute__((address_space(1))) unsigned int*)g,
      (__attribute__((address_space(3))) unsigned int*)l, 16, 0, 0);
}

// ---------------- small prep kernels ----------------

// convert W_ih and W_hh in one launch
__global__ void k_cvt_w(const float* __restrict__ wih, const float* __restrict__ whh,
                        unsigned short* __restrict__ o_ih, unsigned short* __restrict__ o_hh){
  int i = blockIdx.x * blockDim.x + threadIdx.x;   // over 2 * G4*512
  int n1 = G4 * EDIM;
  if (i < n1) o_ih[i] = f2b(wih[i]);
  else { int j = i - n1; if (j < G4 * HDIM) o_hh[j] = f2b(whh[j]); }
}

__global__ void k_cvt_wout(const float* __restrict__ in, unsigned short* __restrict__ out){
  int i = blockIdx.x * blockDim.x + threadIdx.x; // over VPAD*1024
  if (i >= VPAD * 1024) return;
  int r = i >> 10, c = i & 1023;
  float v = (r < VOCAB) ? in[r * 1024 + c] : 0.0f;
  out[i] = f2b(v);
}

__global__ void k_build_xs(const float* __restrict__ img, const float* __restrict__ txt,
                           const float* __restrict__ emb, const int* __restrict__ ans,
                           unsigned short* __restrict__ xs){
  int i = blockIdx.x * blockDim.x + threadIdx.x; // over T*B*E
  if (i >= T_STEPS * BATCH * EDIM) return;
  int e = i & (EDIM - 1);
  int r = i >> 9;              // t*B + b
  int t = r >> 8, b = r & 255;
  float v;
  if (t == 0) v = (e < 256) ? img[b * 256 + e] : txt[b * 256 + (e - 256)];
  else { int tok = ans[b * T_STEPS + (t - 1)]; v = emb[(size_t)tok * EDIM + e]; }
  xs[i] = f2b(v);
}

__global__ void k_init_carry(const float* __restrict__ h0, const float* __restrict__ c0,
                             unsigned short* __restrict__ hx, float* __restrict__ cx){
  int i = blockIdx.x * blockDim.x + threadIdx.x;
  if (i < BATCH * HDIM){ hx[i] = f2b(h0[i]); cx[i] = c0[i]; }
}

// batch_sizes, packed row offsets, total rows, dest->src row map
__global__ void k_lens(const int* __restrict__ lengths, int* __restrict__ bs,
                       int* __restrict__ roff, int* __restrict__ meta,
                       int* __restrict__ rmap){
  __shared__ int s[T_STEPS];
  __shared__ int sroff[T_STEPS + 1];
  int t = threadIdx.x; // 64 threads
  if (t < T_STEPS){
    int c = 0;
    for (int i = 0; i < BATCH; i++) c += (lengths[i] > t) ? 1 : 0;
    s[t] = c; bs[t] = c;
  }
  __syncthreads();
  if (t == 0){
    int acc = 0;
    for (int u = 0; u < T_STEPS; u++){ sroff[u] = acc; roff[u] = acc; acc += s[u]; }
    sroff[T_STEPS] = acc;
    meta[0] = acc;
  }
  __syncthreads();
  int ntot = sroff[T_STEPS];
  for (int r = t; r < T_STEPS * BATCH; r += 64){
    int tt = r >> 8, b = r & 255;
    if (b < s[tt]) rmap[sroff[tt] + b] = r;
  }
  for (int r = ntot + t; r < T_STEPS * BATCH; r += 64) rmap[r] = -1;
}

// ---------------- staged 128x128 GEMM core, BK=64, XOR-swizzled LDS ----------------
template<int K>
__device__ __forceinline__ void gemm_tile(const unsigned short* __restrict__ A,
                                          const unsigned short* __restrict__ B,
                                          int row0, int col0,
                                          unsigned short* As, unsigned short* Bs,
                                          f32x4 acc[4][4]){
  const int tid = threadIdx.x, w = tid >> 6, l = tid & 63;
  const int la = l & 15, lkq = l >> 4;
  const int sr = l >> 3;            // row within 8-row staging group
  const int ss = (l & 7) ^ sr;      // pre-swizzled source slot
  const int wr = (w >> 1) * 64, wc = (w & 1) * 64;
  const unsigned short* gA = A + (size_t)(row0 + w * 32 + sr) * K + ss * 8;
  const unsigned short* gB = B + (size_t)(col0 + w * 32 + sr) * K + ss * 8;
  unsigned short* lA = As + (w * 32) * 64;
  unsigned short* lB = Bs + (w * 32) * 64;
  for (int k0 = 0; k0 < K; k0 += 64){
#pragma unroll
    for (int i = 0; i < 4; i++){
      gload_lds16(gA + (size_t)i * 8 * K + k0, lA + i * 8 * 64);
      gload_lds16(gB + (size_t)i * 8 * K + k0, lB + i * 8 * 64);
    }
    __syncthreads();
#pragma unroll
    for (int kk = 0; kk < 2; kk++){
      bf16x8 a[4], b[4];
#pragma unroll
      for (int i = 0; i < 4; i++){
        int r = wr + i * 16 + la;
        a[i] = *(const bf16x8*)(As + r * 64 + (((kk * 4 + lkq) ^ (r & 7)) << 3));
      }
#pragma unroll
      for (int i = 0; i < 4; i++){
        int r = wc + i * 16 + la;
        b[i] = *(const bf16x8*)(Bs + r * 64 + (((kk * 4 + lkq) ^ (r & 7)) << 3));
      }
#pragma unroll
      for (int mi = 0; mi < 4; mi++)
#pragma unroll
        for (int ni = 0; ni < 4; ni++)
          acc[mi][ni] = __builtin_amdgcn_mfma_f32_16x16x32_bf16(a[mi], b[ni], acc[mi][ni], 0, 0, 0);
    }
    __syncthreads();
  }
}

// ---------------- GEMM 1: XW = xs @ W_ih^T + b_ih + b_hh (bf16 out) ----------------
__global__ __launch_bounds__(256) void k_gemm_xw(const unsigned short* __restrict__ A,
                                                 const unsigned short* __restrict__ W,
                                                 const float* __restrict__ bih,
                                                 const float* __restrict__ bhh,
                                                 unsigned short* __restrict__ C){
  __shared__ unsigned short As[128 * 64], Bs[128 * 64];
  int row0 = blockIdx.x * 128, col0 = blockIdx.y * 128;
  f32x4 acc[4][4] = {};
  gemm_tile<EDIM>(A, W, row0, col0, As, Bs, acc);
  int tid = threadIdx.x, w = tid >> 6, l = tid & 63;
  int la = l & 15, r4 = (l >> 4) * 4;
  int wr = (w >> 1) * 64, wc = (w & 1) * 64;
#pragma unroll
  for (int ni = 0; ni < 4; ni++){
    int col = col0 + wc + ni * 16 + la;
    float bias = bih[col] + bhh[col];
#pragma unroll
    for (int mi = 0; mi < 4; mi++)
#pragma unroll
      for (int j = 0; j < 4; j++){
        int row = row0 + wr + mi * 16 + r4 + j;
        C[(size_t)row * G4 + col] = f2b(acc[mi][ni][j] + bias);
      }
  }
}

// ---------------- fused recurrent step: 512 blocks (16 rows x 16 hcols), wave=gate ----
// All 16 Whh B-fragments hoisted into registers -> one batched latency exposure.
__global__ __launch_bounds__(256, 2) void k_lstm_step(
    const unsigned short* __restrict__ XWt,
    const unsigned short* __restrict__ Whh,
    const unsigned short* __restrict__ hin,
    unsigned short* __restrict__ hout,
    float* __restrict__ cxio,
    unsigned short* __restrict__ hs_t,
    unsigned short* __restrict__ cs_t,
    const unsigned short* __restrict__ hs_m2,
    const unsigned short* __restrict__ cs_m2,
    int do_res){
  __shared__ unsigned short hA[16 * 512];   // swizzled h tile
  __shared__ float gbuf[4][16][17];
  const int w = threadIdx.x >> 6, l = threadIdx.x & 63;
  const int la = l & 15, lkq = l >> 4;
  const int row0 = blockIdx.x * 16;
  const int hc0  = blockIdx.y * 16;
  // stage h tile: wave w stages rows {w, 4+w, 8+w, 12+w}; source slot pre-swizzled
#pragma unroll
  for (int i = 0; i < 4; i++){
    int r = i * 4 + w;
    gload_lds16(hin + (size_t)(row0 + r) * HDIM + ((l ^ (r & 7)) << 3), hA + r * 512);
  }
  // hoist ALL 16 Whh B-fragments (independent, issued back-to-back)
  const unsigned short* Bp = Whh + (size_t)(w * HDIM + hc0 + la) * HDIM + lkq * 8;
  bf16x8 b[16];
#pragma unroll
  for (int kk = 0; kk < 16; kk++) b[kk] = *(const bf16x8*)(Bp + kk * 32);
  // hoist XW (consumed after MFMA loop)
  const int r4 = lkq * 4;
  float x[4];
#pragma unroll
  for (int j = 0; j < 4; j++)
    x[j] = b2f(XWt[(size_t)(row0 + r4 + j) * G4 + w * HDIM + hc0 + la]);
  __syncthreads();
  f32x4 acc = {};
#pragma unroll
  for (int kk = 0; kk < 16; kk++){
    bf16x8 a = *(const bf16x8*)(hA + la * 512 + (((kk * 4 + lkq) ^ (la & 7)) << 3));
    acc = __builtin_amdgcn_mfma_f32_16x16x32_bf16(a, b[kk], acc, 0, 0, 0);
  }
#pragma unroll
  for (int j = 0; j < 4; j++) gbuf[w][r4 + j][la] = acc[j] + x[j];
  __syncthreads();
  {
    int r = threadIdx.x >> 4, c = threadIdx.x & 15;
    size_t p = (size_t)(row0 + r) * HDIM + hc0 + c;
    float gi = gbuf[0][r][c], gf = gbuf[1][r][c], gg = gbuf[2][r][c], go = gbuf[3][r][c];
    float cprev = cxio[p];
    float cy = sigm(gf) * cprev + sigm(gi) * tanhf(gg);
    float hy = sigm(go) * tanhf(cy);
    hs_t[p] = f2b(hy);
    cs_t[p] = f2b(cy);
    float hn = hy, cn = cy;
    if (do_res){ hn += b2f(hs_m2[p]); cn += b2f(cs_m2[p]); }
    hout[p] = f2b(hn);
    cxio[p] = cn;
  }
}

// ---------------- GEMM 2: packed output projection, A gathered via rmap ----------------
__global__ __launch_bounds__(256) void k_gemm_out(const unsigned short* __restrict__ hs,
                                                  const unsigned short* __restrict__ cs,
                                                  const unsigned short* __restrict__ Wo,
                                                  const float* __restrict__ bout,
                                                  const int* __restrict__ meta,
                                                  const int* __restrict__ rmap,
                                                  float* __restrict__ out){
  int ntot = meta[0];
  int row0 = blockIdx.x * 128, col0 = blockIdx.y * 128;
  if (row0 >= ntot) return;
  __shared__ unsigned short As[128 * 64], Bs[128 * 64];
  const int tid = threadIdx.x, w = tid >> 6, l = tid & 63;
  const int la = l & 15, lkq = l >> 4;
  const int sr = l >> 3, ss = (l & 7) ^ sr;
  const int wr = (w >> 1) * 64, wc = (w & 1) * 64;
  int srow[4];
#pragma unroll
  for (int i = 0; i < 4; i++){
    int rr = rmap[row0 + w * 32 + sr + i * 8];
    srow[i] = rr < 0 ? 0 : rr;
  }
  const unsigned short* gB = Wo + (size_t)(col0 + w * 32 + sr) * 1024 + ss * 8;
  unsigned short* lA = As + (w * 32) * 64;
  unsigned short* lB = Bs + (w * 32) * 64;
  f32x4 acc[4][4] = {};
  for (int k0 = 0; k0 < 1024; k0 += 64){
#pragma unroll
    for (int i = 0; i < 4; i++){
      const unsigned short* srcA = (k0 < 512)
          ? hs + (size_t)srow[i] * 512 + k0 + ss * 8
          : cs + (size_t)srow[i] * 512 + (k0 - 512) + ss * 8;
      gload_lds16(srcA, lA + i * 8 * 64);
      gload_lds16(gB + (size_t)i * 8 * 1024 + k0, lB + i * 8 * 64);
    }
    __syncthreads();
#pragma unroll
    for (int kk = 0; kk < 2; kk++){
      bf16x8 a[4], b[4];
#pragma unroll
      for (int i = 0; i < 4; i++){
        int r = wr + i * 16 + la;
        a[i] = *(const bf16x8*)(As + r * 64 + (((kk * 4 + lkq) ^ (r & 7)) << 3));
      }
#pragma unroll
      for (int i = 0; i < 4; i++){
        int r = wc + i * 16 + la;
        b[i] = *(const bf16x8*)(Bs + r * 64 + (((kk * 4 + lkq) ^ (r & 7)) << 3));
      }
#pragma unroll
      for (int mi = 0; mi < 4; mi++)
#pragma unroll
        for (int ni = 0; ni < 4; ni++)
          acc[mi][ni] = __builtin_amdgcn_mfma_f32_16x16x32_bf16(a[mi], b[ni], acc[mi][ni], 0, 0, 0);
    }
    __syncthreads();
  }
  int r4 = (l >> 4) * 4;
#pragma unroll
  for (int ni = 0; ni < 4; ni++){
    int col = col0 + wc + ni * 16 + la;
    if (col >= VOCAB) continue;
    float bias = bout[col];
#pragma unroll
    for (int mi = 0; mi < 4; mi++)
#pragma unroll
      for (int j = 0; j < 4; j++){
        int row = row0 + wr + mi * 16 + r4 + j;
        if (row < ntot) out[(size_t)row * VOCAB + col] = acc[mi][ni][j] + bias;
      }
  }
}

extern "C" void kernel_launch(void* const* d_in, const int* in_sizes, int n_in,
                              void* d_out, int out_size, void* d_ws, size_t ws_size,
                              hipStream_t stream){
  const float* img   = (const float*)d_in[0];
  const float* txt   = (const float*)d_in[1];
  const float* h0    = (const float*)d_in[2];
  const float* c0    = (const float*)d_in[3];
  const float* emb   = (const float*)d_in[4];
  const float* W_ih  = (const float*)d_in[5];
  const float* W_hh  = (const float*)d_in[6];
  const float* b_ih  = (const float*)d_in[7];
  const float* b_hh  = (const float*)d_in[8];
  const float* W_out = (const float*)d_in[9];
  const float* b_out = (const float*)d_in[10];
  const int* answer  = (const int*)d_in[11];
  const int* lengths = (const int*)d_in[12];
  float* out = (float*)d_out;

  char* ws = (char*)d_ws;
  size_t off = 0;
  auto alloc = [&](size_t bytes) -> void* {
    void* p = ws + off; off += (bytes + 255) & ~(size_t)255; return p;
  };
  unsigned short* Wih_b = (unsigned short*)alloc((size_t)G4 * EDIM * 2);
  unsigned short* Whh_b = (unsigned short*)alloc((size_t)G4 * HDIM * 2);
  unsigned short* Wo_b  = (unsigned short*)alloc((size_t)VPAD * 1024 * 2);
  unsigned short* xs    = (unsigned short*)alloc((size_t)T_STEPS * BATCH * EDIM * 2);
  unsigned short* XW    = (unsigned short*)alloc((size_t)T_STEPS * BATCH * G4 * 2);
  unsigned short* hs    = (unsigned short*)alloc((size_t)T_STEPS * BATCH * HDIM * 2);
  unsigned short* cs    = (unsigned short*)alloc((size_t)T_STEPS * BATCH * HDIM * 2);
  unsigned short* hxA   = (unsigned short*)alloc((size_t)BATCH * HDIM * 2);
  unsigned short* hxB   = (unsigned short*)alloc((size_t)BATCH * HDIM * 2);
  float* cx             = (float*)alloc((size_t)BATCH * HDIM * 4);
  int* bsz  = (int*)alloc(T_STEPS * 4);
  int* roff = (int*)alloc(T_STEPS * 4);
  int* meta = (int*)alloc(256);
  int* rmap = (int*)alloc(T_STEPS * BATCH * 4);

  k_cvt_w<<<(2 * G4 * EDIM + 255) / 256, 256, 0, stream>>>(W_ih, W_hh, Wih_b, Whh_b);
  k_cvt_wout<<<(VPAD * 1024 + 255) / 256, 256, 0, stream>>>(W_out, Wo_b);
  k_build_xs<<<(T_STEPS * BATCH * EDIM + 255) / 256, 256, 0, stream>>>(img, txt, emb, answer, xs);
  k_init_carry<<<(BATCH * HDIM + 255) / 256, 256, 0, stream>>>(h0, c0, hxA, cx);
  k_lens<<<1, 64, 0, stream>>>(lengths, bsz, roff, meta, rmap);

  k_gemm_xw<<<dim3(T_STEPS * BATCH / 128, G4 / 128), 256, 0, stream>>>(xs, Wih_b, b_ih, b_hh, XW);

  unsigned short* hbuf[2] = { hxA, hxB };
  for (int t = 0; t < T_STEPS; t++){
    int do_res = (t >= 2 && (t % 3) == 0) ? 1 : 0;
    int tm2 = (t >= 2) ? (t - 2) : 0;
    k_lstm_step<<<dim3(BATCH / 16, HDIM / 16), 256, 0, stream>>>(
        XW + (size_t)t * BATCH * G4, Whh_b, hbuf[t & 1], hbuf[(t + 1) & 1], cx,
        hs + (size_t)t * BATCH * HDIM, cs + (size_t)t * BATCH * HDIM,
        hs + (size_t)tm2 * BATCH * HDIM, cs + (size_t)tm2 * BATCH * HDIM, do_res);
  }

  k_gemm_out<<<dim3(T_STEPS * BATCH / 128, VPAD / 128), 256, 0, stream>>>(hs, cs, Wo_b, b_out, meta, rmap, out);
}